// Round 5
// baseline (761.762 us; speedup 1.0000x reference)
//
#include <hip/hip_runtime.h>

// GraphConvolution (Chebyshev K=5) on MI355X — round 5.
// Change vs round 4: XCD-sliced SpMM. Features (256) split into 8 slices of 32
// (slice-major layout [s][M][32], 64 B/row-slice, 3 MB/slice); slice =
// blockIdx%8 -> XCD via the round-robin dispatch mapping. Each XCD's gathers
// then touch only its own 3 MB slice, which fits the 4 MB per-XCD L2 ->
// gathers become L2 hits instead of ~3.5 TB/s fabric fills (rounds 1-4 showed
// FETCH ~= full gather volume, i.e. zero L2 reuse). Streaming operands (cv,
// sub-row, y, out) use nontemporal load/store to keep the slice resident.

constexpr int M   = 49152;
constexpr int B   = 16;
constexpr int FIN = 16;
constexpr int F1  = 32;
constexpr int K   = 5;
constexpr int FB  = B * FIN;                 // 256 bf16 features per row
constexpr int XBS = M * FIN;                 // per-b stride in x[B,M,FIN]
constexpr size_t SLICEB   = (size_t)M * 64;  // bytes per feature slice
constexpr size_t BUFBYTES = (size_t)M * 512; // bytes per xs_k buffer (8 slices)

typedef short s16x8 __attribute__((ext_vector_type(8)));
typedef float f32x4 __attribute__((ext_vector_type(4)));

#define DEVFN __device__ __forceinline__

DEVFN float bf2f(unsigned short h) {
  union { unsigned int u; float f; } v;
  v.u = (unsigned int)h << 16;
  return v.f;
}
DEVFN float lo2f(unsigned int d) {
  union { unsigned int u; float f; } v; v.u = d << 16; return v.f;
}
DEVFN float hi2f(unsigned int d) {
  union { unsigned int u; float f; } v; v.u = d & 0xffff0000u; return v.f;
}
DEVFN unsigned short f2bf(float f) {   // round-to-nearest-even
  union { float f; unsigned int u; } v;
  v.f = f;
  unsigned int r = (v.u + 0x7FFFu + ((v.u >> 16) & 1u)) >> 16;
  return (unsigned short)r;
}

// ---------------- x -> bf16 slice-major [8][M][32] ----------------
// lane l: s=l>>3, i=l&7 -> features c0=s*32+i*4 .. +3; b=c0>>4, f=c0&15.

__global__ __launch_bounds__(256) void transform_x(const float* __restrict__ x,
                                                   char* __restrict__ x0b) {
  int lane = threadIdx.x & 63;
  int m = blockIdx.x * 4 + (threadIdx.x >> 6);
  int s = lane >> 3, i = lane & 7;
  int b = 2 * s + (i >> 2), f = (i & 3) * 4;
  float4 v = *(const float4*)(x + (size_t)b * XBS + (size_t)m * FIN + f);
  ushort4 r = make_ushort4(f2bf(v.x), f2bf(v.y), f2bf(v.z), f2bf(v.w));
  *(ushort4*)(x0b + (size_t)s * SLICEB + (size_t)m * 64 + i * 8) = r;
}

// ---------------- CSR build ----------------

__global__ __launch_bounds__(256) void hist_kernel(const int* __restrict__ rows,
                                                   int* __restrict__ counts, int nnz) {
  int i = blockIdx.x * 256 + threadIdx.x;
  if (i < nnz) atomicAdd(&counts[rows[i]], 1);
}

DEVFN int wave_incl_scan(int v, int lane) {
#pragma unroll
  for (int off = 1; off < 64; off <<= 1) {
    int t = __shfl_up(v, off);
    if (lane >= off) v += t;
  }
  return v;
}

__global__ __launch_bounds__(1024) void scan_blocks(const int* __restrict__ counts,
                                                    int* __restrict__ row_ptr,
                                                    int* __restrict__ partials) {
  __shared__ int wsum[16];
  int tid = threadIdx.x, lane = tid & 63, w = tid >> 6;
  int i = blockIdx.x * 1024 + tid;
  int s = wave_incl_scan(counts[i], lane);
  if (lane == 63) wsum[w] = s;
  __syncthreads();
  if (tid < 16) {
    int t = wsum[tid];
#pragma unroll
    for (int off = 1; off < 16; off <<= 1) {
      int u = __shfl_up(t, off);
      if (tid >= off) t += u;
    }
    wsum[tid] = t;
  }
  __syncthreads();
  int base = (w > 0) ? wsum[w - 1] : 0;
  s += base;
  row_ptr[i + 1] = s;
  if (tid == 1023) partials[blockIdx.x] = s;
}

__global__ void scan_partials_kernel(int* __restrict__ partials,
                                     int* __restrict__ row_ptr, int nblk) {
  int lane = threadIdx.x;  // 64 threads
  int v = (lane < nblk) ? partials[lane] : 0;
  v = wave_incl_scan(v, lane);
  if (lane < nblk) partials[lane] = v;
  if (lane == 0) row_ptr[0] = 0;
}

__global__ __launch_bounds__(1024) void scan_add_kernel(int* __restrict__ row_ptr,
                                                        const int* __restrict__ partials) {
  if (blockIdx.x == 0) return;
  int i = blockIdx.x * 1024 + threadIdx.x;
  row_ptr[i + 1] += partials[blockIdx.x - 1];
}

__global__ __launch_bounds__(256) void scatter_kernel(const int* __restrict__ rows,
                                                      const int* __restrict__ cols,
                                                      const float* __restrict__ vals,
                                                      const int* __restrict__ row_ptr,
                                                      int* __restrict__ fill,
                                                      int2* __restrict__ cv, int nnz) {
  int i = blockIdx.x * 256 + threadIdx.x;
  if (i < nnz) {
    int r = rows[i];
    int pos = row_ptr[r] + atomicAdd(&fill[r], 1);
    cv[pos] = make_int2(cols[i], __float_as_int(vals[i]));
  }
}

// ---------------- SpMM, XCD-sliced ----------------
// Block: slice s = blockIdx%8 (-> XCD s), rowgroup = blockIdx/8 (64 rows,
// 16/wave). Per row: 4 edge-groups x 16 lanes; lane fl handles features
// (2*fl, 2*fl+1) of the slice (one uint = 2 bf16 per gather). Gathers from the
// block's own slice (L2-resident); cv/sub/y are nontemporal.

template <bool SUB>
__global__ __launch_bounds__(256) void spmm_slice(const char* __restrict__ xsrc,
                                                  const char* __restrict__ ssrc,
                                                  char* __restrict__ y,
                                                  const int* __restrict__ row_ptr,
                                                  const int2* __restrict__ cv) {
  int s  = blockIdx.x & 7;
  int rg = blockIdx.x >> 3;
  int lane = threadIdx.x & 63, wave = threadIdx.x >> 6;
  int grp = lane >> 4, fl = lane & 15;
  int fl4 = fl * 4;
  const char* sbase = xsrc + (size_t)s * SLICEB;
  const char* subbase = ssrc + (size_t)s * SLICEB;
  char* ybase = y + (size_t)s * SLICEB;
  int m0 = rg * 64 + wave * 16;

  for (int mi = 0; mi < 16; ++mi) {
    int m = m0 + mi;
    int beg = row_ptr[m], end = row_ptr[m + 1];
    int nt4 = (end - beg + 3) >> 2;
    float a0 = 0.f, a1 = 0.f;
    int e = beg + grp;
    for (int t = 0; t < nt4; ++t, e += 4) {
      if (e < end) {
        long long ll = __builtin_nontemporal_load((const long long*)(cv + e));
        int c = (int)ll;
        float v = __int_as_float((int)(ll >> 32));
        unsigned int d = *(const unsigned int*)(sbase + (size_t)c * 64 + fl4);
        a0 = fmaf(v, lo2f(d), a0);
        a1 = fmaf(v, hi2f(d), a1);
      }
    }
    a0 += __shfl_xor(a0, 16); a0 += __shfl_xor(a0, 32);
    a1 += __shfl_xor(a1, 16); a1 += __shfl_xor(a1, 32);
    if (grp == 0) {
      if (SUB) {
        unsigned int sv = __builtin_nontemporal_load(
            (const unsigned int*)(subbase + (size_t)m * 64 + fl4));
        a0 = fmaf(2.f, a0, -lo2f(sv));
        a1 = fmaf(2.f, a1, -hi2f(sv));
      }
      unsigned int r = ((unsigned int)f2bf(a1) << 16) | (unsigned int)f2bf(a0);
      __builtin_nontemporal_store(r, (unsigned int*)(ybase + (size_t)m * 64 + fl4));
    }
  }
}

// ---------------- Final contraction via MFMA ----------------
// out[(b*M+m)*32+o] = sum_{k,f} xs_k[m][b*16+f] * kern[(f*5+k)*32+o] + bias[o]
// kk = c*32 + g*8 + j <-> k = 2c+(g>>1), f = (g&1)*8+j; 3 chunks of K=32.
// Slice layout: feature c_int=b*16+f lives in slice b>>1 at byte
// (b&1)*32+(g&1)*16+2j -> per-lane A fragment still 16 B contiguous.

__global__ __launch_bounds__(256) void cheb_gemm_mfma(const char* __restrict__ xs0,
                                                      const float* __restrict__ kern,
                                                      const float* __restrict__ bias,
                                                      float* __restrict__ out) {
  __shared__ unsigned short bl[3][4][32][8];  // [c][g][o][j] = B_kk,o  (6 KB)
  __shared__ float bsl[32];
  int tid = threadIdx.x;
  for (int idx = tid; idx < 3 * 4 * 32 * 8; idx += 256) {
    int j = idx & 7, o = (idx >> 3) & 31, g = (idx >> 8) & 3, c = idx >> 10;
    int k = 2 * c + (g >> 1), f = (g & 1) * 8 + j;
    bl[c][g][o][j] = (k < K) ? f2bf(kern[(f * K + k) * F1 + o]) : (unsigned short)0;
  }
  if (tid < 32) bsl[tid] = bias[tid];
  __syncthreads();

  int lane = tid & 63;
  int w = blockIdx.x * 4 + (tid >> 6);     // 0..6143
  int b = w / 384;                         // 384 waves per batch b
  int mt0 = (w % 384) * 8;                 // first 16-row m-tile of 8

  int row = lane & 15, g = lane >> 4;
  int col = lane & 15;

  s16x8 bf[3][2];
#pragma unroll
  for (int c = 0; c < 3; ++c) {
#pragma unroll
    for (int ot = 0; ot < 2; ++ot)
      bf[c][ot] = *(const s16x8*)(&bl[c][g][col + 16 * ot][0]);
  }
  float bias0 = bsl[col], bias1 = bsl[col + 16];

  size_t lanebyte = (size_t)(b >> 1) * SLICEB + (size_t)row * 64 +
                    (size_t)(b & 1) * 32 + (size_t)(g & 1) * 16;
  int khalf = g >> 1;
  const char* p0 = xs0 + (size_t)(0 + khalf) * BUFBYTES + lanebyte;
  const char* p1 = xs0 + (size_t)(2 + khalf) * BUFBYTES + lanebyte;
  const char* p2 = xs0 + (size_t)(4 + khalf) * BUFBYTES + lanebyte;  // valid g<2

  size_t obase0 = ((size_t)b * M + (size_t)mt0 * 16) * F1;

#pragma unroll 2
  for (int t = 0; t < 8; ++t) {
    size_t moff = (size_t)(mt0 + t) * (16 * 64);
    s16x8 a0 = *(const s16x8*)(p0 + moff);
    s16x8 a1 = *(const s16x8*)(p1 + moff);
    s16x8 a2 = (g < 2) ? *(const s16x8*)(p2 + moff) : (s16x8)0;

    f32x4 acc0 = {0.f, 0.f, 0.f, 0.f};
    f32x4 acc1 = {0.f, 0.f, 0.f, 0.f};
    acc0 = __builtin_amdgcn_mfma_f32_16x16x32_bf16(a0, bf[0][0], acc0, 0, 0, 0);
    acc1 = __builtin_amdgcn_mfma_f32_16x16x32_bf16(a0, bf[0][1], acc1, 0, 0, 0);
    acc0 = __builtin_amdgcn_mfma_f32_16x16x32_bf16(a1, bf[1][0], acc0, 0, 0, 0);
    acc1 = __builtin_amdgcn_mfma_f32_16x16x32_bf16(a1, bf[1][1], acc1, 0, 0, 0);
    acc0 = __builtin_amdgcn_mfma_f32_16x16x32_bf16(a2, bf[2][0], acc0, 0, 0, 0);
    acc1 = __builtin_amdgcn_mfma_f32_16x16x32_bf16(a2, bf[2][1], acc1, 0, 0, 0);

    float* ob = out + obase0 + (size_t)t * (16 * F1);
#pragma unroll
    for (int j = 0; j < 4; ++j) {
      int r = g * 4 + j;
      __builtin_nontemporal_store(acc0[j] + bias0, ob + r * F1 + col);
      __builtin_nontemporal_store(acc1[j] + bias1, ob + r * F1 + col + 16);
    }
  }
}

// ---------------- launch ----------------

extern "C" void kernel_launch(void* const* d_in, const int* in_sizes, int n_in,
                              void* d_out, int out_size, void* d_ws, size_t ws_size,
                              hipStream_t stream) {
  const float* x    = (const float*)d_in[0];
  const int*   rows = (const int*)d_in[1];
  const int*   cols = (const int*)d_in[2];
  const float* vals = (const float*)d_in[3];
  const float* kern = (const float*)d_in[4];
  const float* bias = (const float*)d_in[5];
  float* out = (float*)d_out;
  int nnz = in_sizes[1];

  // workspace layout (~130 MiB); xs buffers contiguous, each slice-major.
  char* x0b = (char*)d_ws;
  char* x1b = x0b + BUFBYTES;
  char* x2b = x1b + BUFBYTES;
  char* x3b = x2b + BUFBYTES;
  char* x4b = x3b + BUFBYTES;
  int* row_ptr  = (int*)(x4b + BUFBYTES);         // M+1 (padded)
  int* counts   = row_ptr + (M + 256);            // M
  int* fill     = counts + M;                     // M (scatter cursor)
  int* partials = fill + M;                       // 48 (padded to 256)
  int2* cv      = (int2*)(partials + 256);        // NNZ packed (col, val)

  int nblk1024 = M / 1024;                        // 48
  int nblkNnz  = (nnz + 255) / 256;

  transform_x<<<M / 4, 256, 0, stream>>>(x, x0b);

  hipMemsetAsync(counts, 0, (size_t)2 * M * 4, stream);   // counts + fill
  hist_kernel<<<nblkNnz, 256, 0, stream>>>(rows, counts, nnz);
  scan_blocks<<<nblk1024, 1024, 0, stream>>>(counts, row_ptr, partials);
  scan_partials_kernel<<<1, 64, 0, stream>>>(partials, row_ptr, nblk1024);
  scan_add_kernel<<<nblk1024, 1024, 0, stream>>>(row_ptr, partials);
  scatter_kernel<<<nblkNnz, 256, 0, stream>>>(rows, cols, vals, row_ptr, fill, cv, nnz);

  // Chebyshev recurrence (bf16, slice-major, fp32 accumulate)
  int spmmGrid = 8 * (M / 64);                    // 6144 blocks
  spmm_slice<false><<<spmmGrid, 256, 0, stream>>>(x0b, nullptr, x1b, row_ptr, cv);
  spmm_slice<true ><<<spmmGrid, 256, 0, stream>>>(x1b, x0b, x2b, row_ptr, cv);
  spmm_slice<true ><<<spmmGrid, 256, 0, stream>>>(x2b, x1b, x3b, row_ptr, cv);
  spmm_slice<true ><<<spmmGrid, 256, 0, stream>>>(x3b, x2b, x4b, row_ptr, cv);

  // final contraction + bias via MFMA: 1536 blocks x 4 waves x 8 m-tiles
  cheb_gemm_mfma<<<1536, 256, 0, stream>>>(x0b, kern, bias, out);

  (void)n_in; (void)out_size; (void)ws_size; (void)in_sizes;
}

// Round 6
// 417.452 us; speedup vs baseline: 1.8248x; 1.8248x over previous
//
#include <hip/hip_runtime.h>

// GraphConvolution (Chebyshev K=5) on MI355X — round 6.
// Round 5 proved XCD-slicing fixes gather traffic (FETCH 185->59 MB) but its
// structure was latency-bound (4-B payloads, serial rows, nt cv loads = ~900cy
// HBM stalls on the dependence chain). Round 6 keeps the [8][M][32] slice
// layout (slice = blockIdx&7 -> XCD) and restores concurrency:
//   - 8 edge slots x 8 lanes x 8 B/lane per row (1 gather instr = 8 edges)
//   - 2 rows in flight per wave (independent load chains), 8 rows/wave
//   - cv packed to u32 (col:16|val-bf16:16) = 1.5 MB/XCD, NORMAL cached loads
//   - sub rows: nt loads prefetched early; y: normal stores (L2-resident for
//     the next pass on the same XCD)

constexpr int M   = 49152;
constexpr int B   = 16;
constexpr int FIN = 16;
constexpr int F1  = 32;
constexpr int K   = 5;
constexpr int XBS = M * FIN;                 // per-b stride in x[B,M,FIN]
constexpr size_t SLICEB   = (size_t)M * 64;  // bytes per feature slice
constexpr size_t BUFBYTES = (size_t)M * 512; // bytes per xs_k buffer (8 slices)

typedef short s16x8 __attribute__((ext_vector_type(8)));
typedef float f32x4 __attribute__((ext_vector_type(4)));
typedef unsigned int u32;
typedef unsigned long long u64;

#define DEVFN __device__ __forceinline__

DEVFN float lo2f(u32 d) {
  union { u32 u; float f; } v; v.u = d << 16; return v.f;
}
DEVFN float hi2f(u32 d) {
  union { u32 u; float f; } v; v.u = d & 0xffff0000u; return v.f;
}
DEVFN unsigned short f2bf(float f) {   // round-to-nearest-even
  union { float f; u32 u; } v;
  v.f = f;
  u32 r = (v.u + 0x7FFFu + ((v.u >> 16) & 1u)) >> 16;
  return (unsigned short)r;
}

// ---------------- x -> bf16 slice-major [8][M][32] ----------------

__global__ __launch_bounds__(256) void transform_x(const float* __restrict__ x,
                                                   char* __restrict__ x0b) {
  int lane = threadIdx.x & 63;
  int m = blockIdx.x * 4 + (threadIdx.x >> 6);
  int s = lane >> 3, i = lane & 7;
  int b = 2 * s + (i >> 2), f = (i & 3) * 4;
  float4 v = *(const float4*)(x + (size_t)b * XBS + (size_t)m * FIN + f);
  ushort4 r = make_ushort4(f2bf(v.x), f2bf(v.y), f2bf(v.z), f2bf(v.w));
  *(ushort4*)(x0b + (size_t)s * SLICEB + (size_t)m * 64 + i * 8) = r;
}

// ---------------- CSR build ----------------

__global__ __launch_bounds__(256) void hist_kernel(const int* __restrict__ rows,
                                                   int* __restrict__ counts, int nnz) {
  int i = blockIdx.x * 256 + threadIdx.x;
  if (i < nnz) atomicAdd(&counts[rows[i]], 1);
}

DEVFN int wave_incl_scan(int v, int lane) {
#pragma unroll
  for (int off = 1; off < 64; off <<= 1) {
    int t = __shfl_up(v, off);
    if (lane >= off) v += t;
  }
  return v;
}

__global__ __launch_bounds__(1024) void scan_blocks(const int* __restrict__ counts,
                                                    int* __restrict__ row_ptr,
                                                    int* __restrict__ partials) {
  __shared__ int wsum[16];
  int tid = threadIdx.x, lane = tid & 63, w = tid >> 6;
  int i = blockIdx.x * 1024 + tid;
  int s = wave_incl_scan(counts[i], lane);
  if (lane == 63) wsum[w] = s;
  __syncthreads();
  if (tid < 16) {
    int t = wsum[tid];
#pragma unroll
    for (int off = 1; off < 16; off <<= 1) {
      int u = __shfl_up(t, off);
      if (tid >= off) t += u;
    }
    wsum[tid] = t;
  }
  __syncthreads();
  int base = (w > 0) ? wsum[w - 1] : 0;
  s += base;
  row_ptr[i + 1] = s;
  if (tid == 1023) partials[blockIdx.x] = s;
}

__global__ void scan_partials_kernel(int* __restrict__ partials,
                                     int* __restrict__ row_ptr, int nblk) {
  int lane = threadIdx.x;  // 64 threads
  int v = (lane < nblk) ? partials[lane] : 0;
  v = wave_incl_scan(v, lane);
  if (lane < nblk) partials[lane] = v;
  if (lane == 0) row_ptr[0] = 0;
}

__global__ __launch_bounds__(1024) void scan_add_kernel(int* __restrict__ row_ptr,
                                                        const int* __restrict__ partials) {
  if (blockIdx.x == 0) return;
  int i = blockIdx.x * 1024 + threadIdx.x;
  row_ptr[i + 1] += partials[blockIdx.x - 1];
}

// cv entry: col (high 16) | val-bf16 (low 16)
__global__ __launch_bounds__(256) void scatter_kernel(const int* __restrict__ rows,
                                                      const int* __restrict__ cols,
                                                      const float* __restrict__ vals,
                                                      const int* __restrict__ row_ptr,
                                                      int* __restrict__ fill,
                                                      u32* __restrict__ cvp, int nnz) {
  int i = blockIdx.x * 256 + threadIdx.x;
  if (i < nnz) {
    int r = rows[i];
    int pos = row_ptr[r] + atomicAdd(&fill[r], 1);
    cvp[pos] = ((u32)cols[i] << 16) | (u32)f2bf(vals[i]);
  }
}

// ---------------- SpMM, XCD-sliced, high-ILP ----------------
// slice s = blockIdx&7 (-> XCD); rowgroup = blockIdx>>3 covers 32 rows
// (8/wave). Per row: 8 edge slots (el = lane>>3) x 8 lanes (q = lane&7,
// features q*4..q*4+3, 8 B each). Two rows (A,B) in flight per wave.
// Reduce over el: shfl_xor 8/16/32 (3 steps x 4 accs).

template <bool SUB>
__global__ __launch_bounds__(256) void spmm_slice(const char* __restrict__ xsrc,
                                                  const char* __restrict__ ssrc,
                                                  char* __restrict__ y,
                                                  const int* __restrict__ row_ptr,
                                                  const u32* __restrict__ cvp) {
  int s  = blockIdx.x & 7;
  int rg = blockIdx.x >> 3;
  int lane = threadIdx.x & 63, wave = threadIdx.x >> 6;
  int el = lane >> 3, q = lane & 7;
  const char* sbase = xsrc + (size_t)s * SLICEB;
  const char* subbase = ssrc + (size_t)s * SLICEB;
  char* ybase = y + (size_t)s * SLICEB;
  int m0 = rg * 32 + wave * 8;
  size_t qb = (size_t)q * 8;

  for (int mi = 0; mi < 8; mi += 2) {
    int mA = m0 + mi, mB = mA + 1;
    int begA = row_ptr[mA];
    int endA = row_ptr[mA + 1];          // == begB
    int endB = row_ptr[mB + 1];

    // prefetch sub rows early (nt: no L2 allocate; off the critical chain)
    u64 svA = 0, svB = 0;
    if (SUB) {
      svA = __builtin_nontemporal_load((const u64*)(subbase + (size_t)mA * 64 + qb));
      svB = __builtin_nontemporal_load((const u64*)(subbase + (size_t)mB * 64 + qb));
    }

    float aA0 = 0.f, aA1 = 0.f, aA2 = 0.f, aA3 = 0.f;
    float aB0 = 0.f, aB1 = 0.f, aB2 = 0.f, aB3 = 0.f;
    int eA = begA + el, eB = endA + el;
    for (;;) {
      bool vA = eA < endA, vB = eB < endB;
      if (!__any(vA || vB)) break;
      if (vA) {
        u32 c = cvp[eA];
        float v = lo2f(c);
        u64 d = *(const u64*)(sbase + (size_t)(c >> 16) * 64 + qb);
        u32 dl = (u32)d, dh = (u32)(d >> 32);
        aA0 = fmaf(v, lo2f(dl), aA0);
        aA1 = fmaf(v, hi2f(dl), aA1);
        aA2 = fmaf(v, lo2f(dh), aA2);
        aA3 = fmaf(v, hi2f(dh), aA3);
      }
      if (vB) {
        u32 c = cvp[eB];
        float v = lo2f(c);
        u64 d = *(const u64*)(sbase + (size_t)(c >> 16) * 64 + qb);
        u32 dl = (u32)d, dh = (u32)(d >> 32);
        aB0 = fmaf(v, lo2f(dl), aB0);
        aB1 = fmaf(v, hi2f(dl), aB1);
        aB2 = fmaf(v, lo2f(dh), aB2);
        aB3 = fmaf(v, hi2f(dh), aB3);
      }
      eA += 8; eB += 8;
    }

#pragma unroll
    for (int msk = 8; msk <= 32; msk <<= 1) {
      aA0 += __shfl_xor(aA0, msk); aA1 += __shfl_xor(aA1, msk);
      aA2 += __shfl_xor(aA2, msk); aA3 += __shfl_xor(aA3, msk);
      aB0 += __shfl_xor(aB0, msk); aB1 += __shfl_xor(aB1, msk);
      aB2 += __shfl_xor(aB2, msk); aB3 += __shfl_xor(aB3, msk);
    }

    if (el == 0) {
      if (SUB) {
        u32 sl = (u32)svA, sh = (u32)(svA >> 32);
        aA0 = fmaf(2.f, aA0, -lo2f(sl)); aA1 = fmaf(2.f, aA1, -hi2f(sl));
        aA2 = fmaf(2.f, aA2, -lo2f(sh)); aA3 = fmaf(2.f, aA3, -hi2f(sh));
        sl = (u32)svB; sh = (u32)(svB >> 32);
        aB0 = fmaf(2.f, aB0, -lo2f(sl)); aB1 = fmaf(2.f, aB1, -hi2f(sl));
        aB2 = fmaf(2.f, aB2, -lo2f(sh)); aB3 = fmaf(2.f, aB3, -hi2f(sh));
      }
      uint2 rA, rB;
      rA.x = ((u32)f2bf(aA1) << 16) | (u32)f2bf(aA0);
      rA.y = ((u32)f2bf(aA3) << 16) | (u32)f2bf(aA2);
      rB.x = ((u32)f2bf(aB1) << 16) | (u32)f2bf(aB0);
      rB.y = ((u32)f2bf(aB3) << 16) | (u32)f2bf(aB2);
      *(uint2*)(ybase + (size_t)mA * 64 + qb) = rA;
      *(uint2*)(ybase + (size_t)mB * 64 + qb) = rB;
    }
  }
}

// ---------------- Final contraction via MFMA ----------------
// out[(b*M+m)*32+o] = sum_{k,f} xs_k[m][b*16+f] * kern[(f*5+k)*32+o] + bias[o]
// kk = c*32 + g*8 + j <-> k = 2c+(g>>1), f = (g&1)*8+j; 3 chunks of K=32.
// Slice layout: feature b*16+f lives in slice b>>1 at byte (b&1)*32+f*2.

__global__ __launch_bounds__(256) void cheb_gemm_mfma(const char* __restrict__ xs0,
                                                      const float* __restrict__ kern,
                                                      const float* __restrict__ bias,
                                                      float* __restrict__ out) {
  __shared__ unsigned short bl[3][4][32][8];  // [c][g][o][j] = B_kk,o  (6 KB)
  __shared__ float bsl[32];
  int tid = threadIdx.x;
  for (int idx = tid; idx < 3 * 4 * 32 * 8; idx += 256) {
    int j = idx & 7, o = (idx >> 3) & 31, g = (idx >> 8) & 3, c = idx >> 10;
    int k = 2 * c + (g >> 1), f = (g & 1) * 8 + j;
    bl[c][g][o][j] = (k < K) ? f2bf(kern[(f * K + k) * F1 + o]) : (unsigned short)0;
  }
  if (tid < 32) bsl[tid] = bias[tid];
  __syncthreads();

  int lane = tid & 63;
  int w = blockIdx.x * 4 + (tid >> 6);     // 0..6143
  int b = w / 384;                         // 384 waves per batch b
  int mt0 = (w % 384) * 8;                 // first 16-row m-tile of 8

  int row = lane & 15, g = lane >> 4;
  int col = lane & 15;

  s16x8 bf[3][2];
#pragma unroll
  for (int c = 0; c < 3; ++c) {
#pragma unroll
    for (int ot = 0; ot < 2; ++ot)
      bf[c][ot] = *(const s16x8*)(&bl[c][g][col + 16 * ot][0]);
  }
  float bias0 = bsl[col], bias1 = bsl[col + 16];

  size_t lanebyte = (size_t)(b >> 1) * SLICEB + (size_t)row * 64 +
                    (size_t)(b & 1) * 32 + (size_t)(g & 1) * 16;
  int khalf = g >> 1;
  const char* p0 = xs0 + (size_t)(0 + khalf) * BUFBYTES + lanebyte;
  const char* p1 = xs0 + (size_t)(2 + khalf) * BUFBYTES + lanebyte;
  const char* p2 = xs0 + (size_t)(4 + khalf) * BUFBYTES + lanebyte;  // valid g<2

  size_t obase0 = ((size_t)b * M + (size_t)mt0 * 16) * F1;

#pragma unroll 2
  for (int t = 0; t < 8; ++t) {
    size_t moff = (size_t)(mt0 + t) * (16 * 64);
    s16x8 a0 = *(const s16x8*)(p0 + moff);
    s16x8 a1 = *(const s16x8*)(p1 + moff);
    s16x8 a2 = (g < 2) ? *(const s16x8*)(p2 + moff) : (s16x8)0;

    f32x4 acc0 = {0.f, 0.f, 0.f, 0.f};
    f32x4 acc1 = {0.f, 0.f, 0.f, 0.f};
    acc0 = __builtin_amdgcn_mfma_f32_16x16x32_bf16(a0, bf[0][0], acc0, 0, 0, 0);
    acc1 = __builtin_amdgcn_mfma_f32_16x16x32_bf16(a0, bf[0][1], acc1, 0, 0, 0);
    acc0 = __builtin_amdgcn_mfma_f32_16x16x32_bf16(a1, bf[1][0], acc0, 0, 0, 0);
    acc1 = __builtin_amdgcn_mfma_f32_16x16x32_bf16(a1, bf[1][1], acc1, 0, 0, 0);
    acc0 = __builtin_amdgcn_mfma_f32_16x16x32_bf16(a2, bf[2][0], acc0, 0, 0, 0);
    acc1 = __builtin_amdgcn_mfma_f32_16x16x32_bf16(a2, bf[2][1], acc1, 0, 0, 0);

    float* ob = out + obase0 + (size_t)t * (16 * F1);
#pragma unroll
    for (int j = 0; j < 4; ++j) {
      int r = g * 4 + j;
      __builtin_nontemporal_store(acc0[j] + bias0, ob + r * F1 + col);
      __builtin_nontemporal_store(acc1[j] + bias1, ob + r * F1 + col + 16);
    }
  }
}

// ---------------- launch ----------------

extern "C" void kernel_launch(void* const* d_in, const int* in_sizes, int n_in,
                              void* d_out, int out_size, void* d_ws, size_t ws_size,
                              hipStream_t stream) {
  const float* x    = (const float*)d_in[0];
  const int*   rows = (const int*)d_in[1];
  const int*   cols = (const int*)d_in[2];
  const float* vals = (const float*)d_in[3];
  const float* kern = (const float*)d_in[4];
  const float* bias = (const float*)d_in[5];
  float* out = (float*)d_out;
  int nnz = in_sizes[1];

  // workspace layout (~122 MiB); xs buffers contiguous, each slice-major.
  char* x0b = (char*)d_ws;
  char* x1b = x0b + BUFBYTES;
  char* x2b = x1b + BUFBYTES;
  char* x3b = x2b + BUFBYTES;
  char* x4b = x3b + BUFBYTES;
  int* row_ptr  = (int*)(x4b + BUFBYTES);         // M+1 (padded)
  int* counts   = row_ptr + (M + 256);            // M
  int* fill     = counts + M;                     // M (scatter cursor)
  int* partials = fill + M;                       // 48 (padded to 256)
  u32* cvp      = (u32*)(partials + 256);         // NNZ packed (col<<16|val-bf16)

  int nblk1024 = M / 1024;                        // 48
  int nblkNnz  = (nnz + 255) / 256;

  transform_x<<<M / 4, 256, 0, stream>>>(x, x0b);

  hipMemsetAsync(counts, 0, (size_t)2 * M * 4, stream);   // counts + fill
  hist_kernel<<<nblkNnz, 256, 0, stream>>>(rows, counts, nnz);
  scan_blocks<<<nblk1024, 1024, 0, stream>>>(counts, row_ptr, partials);
  scan_partials_kernel<<<1, 64, 0, stream>>>(partials, row_ptr, nblk1024);
  scan_add_kernel<<<nblk1024, 1024, 0, stream>>>(row_ptr, partials);
  scatter_kernel<<<nblkNnz, 256, 0, stream>>>(rows, cols, vals, row_ptr, fill, cvp, nnz);

  // Chebyshev recurrence (bf16, slice-major, fp32 accumulate)
  int spmmGrid = 8 * (M / 32);                    // 12288 blocks
  spmm_slice<false><<<spmmGrid, 256, 0, stream>>>(x0b, nullptr, x1b, row_ptr, cvp);
  spmm_slice<true ><<<spmmGrid, 256, 0, stream>>>(x1b, x0b, x2b, row_ptr, cvp);
  spmm_slice<true ><<<spmmGrid, 256, 0, stream>>>(x2b, x1b, x3b, row_ptr, cvp);
  spmm_slice<true ><<<spmmGrid, 256, 0, stream>>>(x3b, x2b, x4b, row_ptr, cvp);

  // final contraction + bias via MFMA: 1536 blocks x 4 waves x 8 m-tiles
  cheb_gemm_mfma<<<1536, 256, 0, stream>>>(x0b, kern, bias, out);

  (void)n_in; (void)out_size; (void)ws_size; (void)in_sizes;
}